// Round 4
// baseline (76016.791 us; speedup 1.0000x reference)
//
#include <hip/hip_runtime.h>

#define NHIDC 1024
#define BSZ   128
#define TLEN  256
#define SLOT  (BSZ*NHIDC)   // 131072 elements per state slot
#define NBLK  256
#define WSZ   ((size_t)2048*1024)   // bf16 elements per gene weight matrix

using bf16x8 = __attribute__((ext_vector_type(8))) short;
using f32x4  = __attribute__((ext_vector_type(4))) float;

__device__ inline short f2bf(float f){
  union {float f; unsigned u;} v; v.f = f;
  unsigned u = v.u;
  unsigned r = u + 0x7fffu + ((u >> 16) & 1u);
  return (short)(r >> 16);
}

__device__ inline float bact(int act, float x){
  switch(act){
    case 0: return tanhf(x);
    case 1: return 1.f/(1.f+__expf(-x));
    case 2: return x > 0.f ? x : 0.f;
    default: return x;
  }
}

// Transpose-convert: D[n][k] (bf16) = S[k][n] (f32), S is K x 2048, per blockIdx.z matrix.
__global__ __launch_bounds__(256) void transpose_bf16(const float* __restrict__ src,
                                                      short* __restrict__ dst, int K){
  const size_t mat = blockIdx.z;
  const float* S = src + mat * (size_t)K * 2048;
  short* D = dst + mat * (size_t)K * 2048;
  __shared__ float tile[32][33];
  int n0 = blockIdx.x * 32;
  int k0 = blockIdx.y * 32;
  int tx = threadIdx.x & 31, ty = threadIdx.x >> 5;
  #pragma unroll
  for (int i=0;i<4;i++){
    tile[ty + i*8][tx] = S[(size_t)(k0 + ty + i*8)*2048 + n0 + tx];
  }
  __syncthreads();
  #pragma unroll
  for (int i=0;i<4;i++){
    int n = n0 + ty + i*8;
    D[(size_t)n*K + k0 + tx] = f2bf(tile[tx][ty + i*8]);
  }
}

// fp32 -> bf16 bulk convert (for initial h)
__global__ __launch_bounds__(256) void f32_to_bf16(const float* __restrict__ src,
                                                   short* __restrict__ dst){
  int i = (blockIdx.x*256 + threadIdx.x)*4;
  float4 v = *(const float4*)(src + i);
  short4 o;
  o.x = f2bf(v.x); o.y = f2bf(v.y); o.z = f2bf(v.z); o.w = f2bf(v.w);
  *(short4*)(dst + i) = o;
}

// Two-level sense-reversing grid barrier, 256 blocks = 16 groups x 16.
// bar layout (unsigned, 128B-spaced lines): gen = bar[0]; root = bar[32];
// group g = bar[64 + g*32]. All zeroed before launch.
__device__ inline void gbar(unsigned* bar, unsigned& gen){
  __syncthreads();
  if (threadIdx.x == 0){
    __threadfence();                       // release: publish this block's stores
    const int g = (int)blockIdx.x >> 4;
    bool released = false;
    unsigned a = __hip_atomic_fetch_add(&bar[64 + g*32], 1u,
                                        __ATOMIC_ACQ_REL, __HIP_MEMORY_SCOPE_AGENT);
    if (a == 15u){
      __hip_atomic_store(&bar[64 + g*32], 0u, __ATOMIC_RELAXED, __HIP_MEMORY_SCOPE_AGENT);
      unsigned r = __hip_atomic_fetch_add(&bar[32], 1u,
                                          __ATOMIC_ACQ_REL, __HIP_MEMORY_SCOPE_AGENT);
      if (r == 15u){
        __hip_atomic_store(&bar[32], 0u, __ATOMIC_RELAXED, __HIP_MEMORY_SCOPE_AGENT);
        __hip_atomic_store(&bar[0], gen + 1u, __ATOMIC_RELEASE, __HIP_MEMORY_SCOPE_AGENT);
        released = true;
      }
    }
    if (!released){
      unsigned cur;
      do {
        __builtin_amdgcn_s_sleep(2);
        cur = __hip_atomic_load(&bar[0], __ATOMIC_ACQUIRE, __HIP_MEMORY_SCOPE_AGENT);
      } while (cur <= gen);
    }
    __threadfence();                       // acquire: invalidate before next reads
  }
  __syncthreads();
  gen++;
}

// One 16-row x 16-paired-col tile of ch = A @ W, K=1024, 4-wave K-split + LDS reduce.
// Returns (cv, hv) for this thread's element (row = rowbase+q*4+wave, col = col0+m).
__device__ inline float2 mmtile(const short* __restrict__ Abase,  // bf16, row stride 1024
                                const short* __restrict__ W,      // bf16 [2048][1024]
                                int rowbase, int col0,
                                int lane, int wave, int m, int q,
                                float red[][64][9])
{
  const short* wC = W + (size_t)(col0 + m) * 1024;
  const short* wH = wC + (size_t)1024 * 1024;
  const short* ap = Abase + (size_t)(rowbase + m) * NHIDC;
  const int kw0 = wave * 256;
  f32x4 accC = {0.f,0.f,0.f,0.f};
  f32x4 accH = {0.f,0.f,0.f,0.f};
  #pragma unroll
  for (int k0 = 0; k0 < 256; k0 += 32){
    const int k = kw0 + k0 + q*8;
    bf16x8 a  = *(const bf16x8*)(ap + k);
    bf16x8 bC = *(const bf16x8*)(wC + k);
    bf16x8 bH = *(const bf16x8*)(wH + k);
    accC = __builtin_amdgcn_mfma_f32_16x16x32_bf16(a, bC, accC, 0, 0, 0);
    accH = __builtin_amdgcn_mfma_f32_16x16x32_bf16(a, bH, accH, 0, 0, 0);
  }
  __syncthreads();                       // protect red against previous tile's readers
  #pragma unroll
  for (int i=0;i<4;i++){
    red[wave][lane][i]   = accC[i];
    red[wave][lane][4+i] = accH[i];
  }
  __syncthreads();
  float cv = red[0][lane][wave]   + red[1][lane][wave]
           + red[2][lane][wave]   + red[3][lane][wave];
  float hv = red[0][lane][4+wave] + red[1][lane][4+wave]
           + red[2][lane][4+wave] + red[3][lane][4+wave];
  return make_float2(cv, hv);
}

__device__ inline float gatef(float2 ch, int act, float sp){
  float cg_ = 1.f/(1.f+__expf(-ch.x));
  float hh = bact(act, ch.y);
  return sp + cg_*(hh - sp);
}

// One gene over this block's two 16-col subtiles.
__device__ inline void gene2(const float* __restrict__ spf,   // sprev fp32 slot base
                             const short* __restrict__ Ab,    // sprev bf16 slot base
                             float* __restrict__ sof,         // sout fp32 slot base
                             short* __restrict__ sob,         // sout bf16 base or nullptr
                             const short* __restrict__ W, int act,
                             int rowbase, int colbase,
                             int lane, int wave, int m, int q,
                             size_t offb, float red[][64][9])
{
  #pragma unroll
  for (int hsub=0; hsub<2; hsub++){
    const int col0 = colbase + hsub*16;
    const size_t off = offb + hsub*16;
    float2 ch = mmtile(Ab, W, rowbase, col0, lane, wave, m, q, red);
    float sp = spf[off];
    float so = gatef(ch, act, sp);
    sof[off] = so;
    if (sob) sob[off] = f2bf(so);
  }
}

// Persistent kernel: all 256 timesteps, 5 grid barriers per step.
// Block b: rowtile r = b>>5 (16 rows), colgroup c = b&31 (32 paired cols).
// NOTE: XCD = b%8 = c%8, so each XCD always touches the same W columns -> L2-resident.
// sbf slot map (bf16 A-operands only): s0->0, s1->1, s2->2, s3->3, s5->4, h->5.
__global__ __launch_bounds__(256) void rnn_persistent(
    float* __restrict__ states, short* __restrict__ sbf,
    const short* __restrict__ W0T, const short* __restrict__ WsT,
    const float* __restrict__ x, float* __restrict__ out,
    unsigned* __restrict__ bar)
{
  __shared__ float red[4][64][9];
  const int lane = threadIdx.x & 63;
  const int wave = threadIdx.x >> 6;
  const int m = lane & 15;
  const int q = lane >> 4;
  const int rowbase = ((int)blockIdx.x >> 5) * 16;
  const int colbase = ((int)blockIdx.x & 31) * 32;
  const int brow = rowbase + q*4 + wave;              // output row this thread finalizes
  const size_t offb = (size_t)brow*NHIDC + colbase + m;
  unsigned gen = 0;

  for (int t = 0; t < TLEN; t++){
    // ---- phase 1: stage0  ch=[x_t|h]@W0 ; s0 = h + sig(cC)*(tanh(cH)-h) ----
    #pragma unroll
    for (int hsub=0; hsub<2; hsub++){
      const int col0 = colbase + hsub*16;
      const size_t off = offb + hsub*16;
      const short* wC = W0T + (size_t)(col0 + m) * 2048;
      const short* wH = wC + (size_t)1024 * 2048;
      const int kw0 = wave * 512;
      f32x4 accC = {0.f,0.f,0.f,0.f};
      f32x4 accH = {0.f,0.f,0.f,0.f};
      if (wave < 2){
        // x half (k in [0,1024)): fp32 load + convert
        const float* xp = x + ((size_t)(rowbase + m)*TLEN + t)*NHIDC;
        #pragma unroll
        for (int k0 = 0; k0 < 512; k0 += 32){
          const int k = kw0 + k0 + q*8;
          float4 ua = *(const float4*)(xp + k);
          float4 ub = *(const float4*)(xp + k + 4);
          bf16x8 a;
          a[0]=f2bf(ua.x); a[1]=f2bf(ua.y); a[2]=f2bf(ua.z); a[3]=f2bf(ua.w);
          a[4]=f2bf(ub.x); a[5]=f2bf(ub.y); a[6]=f2bf(ub.z); a[7]=f2bf(ub.w);
          bf16x8 bC = *(const bf16x8*)(wC + k);
          bf16x8 bH = *(const bf16x8*)(wH + k);
          accC = __builtin_amdgcn_mfma_f32_16x16x32_bf16(a, bC, accC, 0, 0, 0);
          accH = __builtin_amdgcn_mfma_f32_16x16x32_bf16(a, bH, accH, 0, 0, 0);
        }
      } else {
        // h half (k in [1024,2048)): bf16 h in sbf slot 5
        const short* hp = sbf + (size_t)5*SLOT + (size_t)(rowbase + m)*NHIDC - 1024;
        #pragma unroll
        for (int k0 = 0; k0 < 512; k0 += 32){
          const int k = kw0 + k0 + q*8;
          bf16x8 a  = *(const bf16x8*)(hp + k);
          bf16x8 bC = *(const bf16x8*)(wC + k);
          bf16x8 bH = *(const bf16x8*)(wH + k);
          accC = __builtin_amdgcn_mfma_f32_16x16x32_bf16(a, bC, accC, 0, 0, 0);
          accH = __builtin_amdgcn_mfma_f32_16x16x32_bf16(a, bH, accH, 0, 0, 0);
        }
      }
      __syncthreads();
      #pragma unroll
      for (int i=0;i<4;i++){
        red[wave][lane][i]   = accC[i];
        red[wave][lane][4+i] = accH[i];
      }
      __syncthreads();
      float cv = red[0][lane][wave]   + red[1][lane][wave]
               + red[2][lane][wave]   + red[3][lane][wave];
      float hv = red[0][lane][4+wave] + red[1][lane][4+wave]
               + red[2][lane][4+wave] + red[3][lane][4+wave];
      float sp = states[(size_t)9*SLOT + off];
      float cg_ = 1.f/(1.f+__expf(-cv));
      float hh = tanhf(hv);
      float so = sp + cg_*(hh - sp);
      states[off] = so;                   // fp32 slot 0
      sbf[off] = f2bf(so);                // bf16 slot 0
    }
    gbar(bar, gen);

    // ---- phase 2: g0 (s0 -> s1, sigmoid) ----
    gene2(states, sbf, states + (size_t)1*SLOT, sbf + (size_t)1*SLOT,
          WsT + 0*WSZ, 1, rowbase, colbase, lane, wave, m, q, offb, red);
    gbar(bar, gen);

    // ---- phase 3: g1 (s1->s2, relu), g2 (s1->s3, relu), g3 (s1->s4, identity) ----
    gene2(states + (size_t)1*SLOT, sbf + (size_t)1*SLOT,
          states + (size_t)2*SLOT, sbf + (size_t)2*SLOT,
          WsT + 1*WSZ, 2, rowbase, colbase, lane, wave, m, q, offb, red);
    gene2(states + (size_t)1*SLOT, sbf + (size_t)1*SLOT,
          states + (size_t)3*SLOT, sbf + (size_t)3*SLOT,
          WsT + 2*WSZ, 2, rowbase, colbase, lane, wave, m, q, offb, red);
    gene2(states + (size_t)1*SLOT, sbf + (size_t)1*SLOT,
          states + (size_t)4*SLOT, nullptr,
          WsT + 3*WSZ, 3, rowbase, colbase, lane, wave, m, q, offb, red);
    gbar(bar, gen);

    // ---- phase 4: g4 (s2->s5, tanh), g6 (s3->s7, tanh) ----
    gene2(states + (size_t)2*SLOT, sbf + (size_t)2*SLOT,
          states + (size_t)5*SLOT, sbf + (size_t)4*SLOT,
          WsT + 4*WSZ, 0, rowbase, colbase, lane, wave, m, q, offb, red);
    gene2(states + (size_t)3*SLOT, sbf + (size_t)3*SLOT,
          states + (size_t)7*SLOT, nullptr,
          WsT + 6*WSZ, 0, rowbase, colbase, lane, wave, m, q, offb, red);
    gbar(bar, gen);

    // ---- phase 5: g5 (s5->s6, sigmoid), g7 (s5->s8, relu), fused mean -> h, out ----
    #pragma unroll
    for (int hsub=0; hsub<2; hsub++){
      const int col0 = colbase + hsub*16;
      const size_t off = offb + hsub*16;
      float2 c5 = mmtile(sbf + (size_t)4*SLOT, WsT + 5*WSZ,
                         rowbase, col0, lane, wave, m, q, red);
      float sp5 = states[(size_t)5*SLOT + off];
      float s6 = gatef(c5, 1, sp5);
      float2 c7 = mmtile(sbf + (size_t)4*SLOT, WsT + 7*WSZ,
                         rowbase, col0, lane, wave, m, q, red);
      float s8 = gatef(c7, 2, sp5);
      float sum = s6 + s8
                + states[(size_t)1*SLOT + off] + states[(size_t)2*SLOT + off]
                + states[(size_t)3*SLOT + off] + states[(size_t)4*SLOT + off]
                + sp5                           + states[(size_t)7*SLOT + off];
      float h = sum * 0.125f;
      states[(size_t)9*SLOT + off] = h;
      sbf[(size_t)5*SLOT + off] = f2bf(h);
      out[((size_t)brow*TLEN + t)*NHIDC + col0 + m] = h;
      if (t == TLEN-1) out[(size_t)BSZ*TLEN*NHIDC + off] = h;
    }
    gbar(bar, gen);   // h complete before next step's stage0
  }
}

extern "C" void kernel_launch(void* const* d_in, const int* in_sizes, int n_in,
                              void* d_out, int out_size, void* d_ws, size_t ws_size,
                              hipStream_t stream) {
  const float* x  = (const float*)d_in[0];   // (128, 256, 1024)
  const float* h0 = (const float*)d_in[1];   // (1, 128, 1024)
  const float* W0 = (const float*)d_in[2];   // (2048, 2048)
  const float* Ws = (const float*)d_in[3];   // (8, 1024, 2048)
  float* out = (float*)d_out;

  // ws layout: [0) barrier (4KB used) | [1MB) W0T bf16 8MB | [9MB) WsT bf16 32MB |
  //            [41MB) states fp32 10 slots (5MB) | [46MB) sbf bf16 6 slots (1.5MB)
  char* wsb = (char*)d_ws;
  unsigned* bar = (unsigned*)wsb;
  short* W0T = (short*)(wsb + (size_t)1*1024*1024);
  short* WsT = (short*)(wsb + (size_t)9*1024*1024);
  float* states = (float*)(wsb + (size_t)41*1024*1024);
  short* sbf = (short*)(wsb + (size_t)46*1024*1024);

  hipMemsetAsync(bar, 0, 4096, stream);
  transpose_bf16<<<dim3(64,64,1),256,0,stream>>>(W0, W0T, 2048);
  transpose_bf16<<<dim3(64,32,8),256,0,stream>>>(Ws, WsT, 1024);

  hipMemcpyAsync(states + (size_t)9*SLOT, h0, (size_t)SLOT*sizeof(float),
                 hipMemcpyDeviceToDevice, stream);
  f32_to_bf16<<<dim3(128,1),256,0,stream>>>(h0, sbf + (size_t)5*SLOT);

  rnn_persistent<<<dim3(NBLK), dim3(256), 0, stream>>>(states, sbf, W0T, WsT, x, out, bar);
}